// Round 8
// baseline (317.069 us; speedup 1.0000x reference)
//
#include <hip/hip_runtime.h>
#include <math.h>

#define B_ 4
#define N_ 2048
#define C_ 64
#define H_ 16
#define D_ 64
#define HID 1024

// fold attention scale (1/8) and log2(e) into Q so softmax uses exp2 directly
#define QSCALE 0.18033688011112042f  // 0.125 * 1.4426950408889634

typedef short bf16x8 __attribute__((ext_vector_type(8)));
typedef unsigned short u16x8 __attribute__((ext_vector_type(8)));
typedef float f32x4 __attribute__((ext_vector_type(4)));

#define MFMA(a, b, c) __builtin_amdgcn_mfma_f32_16x16x32_bf16((a), (b), (c), 0, 0, 0)

typedef __attribute__((address_space(3))) void lds_t;
typedef const __attribute__((address_space(1))) void gbl_t;
// async global->LDS, 16B/lane; LDS dest = wave-uniform base + lane*16
#define ASYNC16(g, l) __builtin_amdgcn_global_load_lds((gbl_t*)(g), (lds_t*)(l), 16, 0, 0)

static __device__ __forceinline__ unsigned short f2bf(float f) {
  unsigned u = __float_as_uint(f);
  u += 0x7FFFu + ((u >> 16) & 1u);  // round-to-nearest-even
  return (unsigned short)(u >> 16);
}
static __device__ __forceinline__ float bf2f(unsigned short h) {
  return __uint_as_float((unsigned)h << 16);
}

// ---------------------------------------------------------------------------
// Kernel 0: convert out_w [1024][64] f32 -> W2T packed (hi<<16|lo) [64][1024]
// ---------------------------------------------------------------------------
__global__ __launch_bounds__(256) void w2conv(const float* __restrict__ W2,
                                              unsigned* __restrict__ W2TP) {
  int idx = blockIdx.x * 256 + threadIdx.x;  // 65536 total
  int k = idx & 1023, col = idx >> 10;
  float v = W2[(size_t)k * 64 + col];
  unsigned short hi = f2bf(v);
  unsigned short lo = f2bf(v - bf2f(hi));
  W2TP[(size_t)col * 1024 + k] = ((unsigned)hi << 16) | lo;
}

// ---------------------------------------------------------------------------
// Kernel 1: QKV projection (K=64) + split into bf16 hi/lo arrays.
// Q,K layout [B][H][N][D]; V layout TRANSPOSED [B][H][D][N].
// Round-8: VT stores go through an LDS transpose so global stores are
// coalesced uint4 rows (was: 4B dwords at 32KB lane stride -> ~16x write
// transaction inflation, the dominant cost of this kernel).
// ---------------------------------------------------------------------------
__global__ __launch_bounds__(256) void qkv_kernel(
    const float* __restrict__ X, const float* __restrict__ W,
    const float* __restrict__ bias,
    unsigned short* __restrict__ Qhi, unsigned short* __restrict__ Qlo,
    unsigned short* __restrict__ Khi, unsigned short* __restrict__ Klo,
    unsigned short* __restrict__ Vhi, unsigned short* __restrict__ Vlo) {
  __shared__ float Xl[32][68];
  __shared__ float Wl[64][132];
  __shared__ unsigned sTh[128][17];  // V transpose: [col][tokpair] packed 2 toks
  __shared__ unsigned sTl[128][17];
  const int t = threadIdx.x;
  const int ct = blockIdx.x;
  const int tt = blockIdx.y;

#pragma unroll
  for (int i = 0; i < 2; ++i) {
    int idx = t + 256 * i;
    int tok = idx >> 4, f4 = (idx & 15) * 4;
    *(f32x4*)&Xl[tok][f4] = *(const f32x4*)&X[(size_t)(tt * 32 + tok) * 64 + f4];
  }
#pragma unroll
  for (int i = 0; i < 8; ++i) {
    int idx = t + 256 * i;
    int c = idx >> 5, f4 = (idx & 31) * 4;
    *(f32x4*)&Wl[c][f4] = *(const f32x4*)&W[(size_t)c * 3072 + ct * 128 + f4];
  }
  __syncthreads();

  const int tok2 = t >> 4;  // 16 groups of 2 tokens
  const int colg = t & 15;  // 16 groups of 8 cols
  float acc[2][8];
#pragma unroll
  for (int i = 0; i < 2; ++i)
#pragma unroll
    for (int c = 0; c < 8; ++c) acc[i][c] = 0.f;

#pragma unroll 4
  for (int c4 = 0; c4 < 64; c4 += 4) {
    f32x4 x0 = *(const f32x4*)&Xl[tok2 * 2][c4];
    f32x4 x1 = *(const f32x4*)&Xl[tok2 * 2 + 1][c4];
#pragma unroll
    for (int j = 0; j < 4; ++j) {
      f32x4 wa = *(const f32x4*)&Wl[c4 + j][colg * 8];
      f32x4 wb = *(const f32x4*)&Wl[c4 + j][colg * 8 + 4];
#pragma unroll
      for (int cc = 0; cc < 4; ++cc) {
        acc[0][cc] += x0[j] * wa[cc];
        acc[0][cc + 4] += x0[j] * wb[cc];
        acc[1][cc] += x1[j] * wa[cc];
        acc[1][cc + 4] += x1[j] * wb[cc];
      }
    }
  }

  const int s = ct >> 3;  // 0=q 1=k 2=v (uniform per block)
  unsigned short* hiA = (s == 0) ? Qhi : ((s == 1) ? Khi : Vhi);
  unsigned short* loA = (s == 0) ? Qlo : ((s == 1) ? Klo : Vlo);
  const float scale = (s == 0) ? QSCALE : 1.0f;
  const int col0 = ct * 128 + colg * 8;
  const int hh = (col0 >> 6) & 15, d0 = col0 & 63;
  float bia[8];
#pragma unroll
  for (int cc = 0; cc < 8; ++cc) bia[cc] = bias[col0 + cc];

  unsigned short hi_[2][8], lo_[2][8];
#pragma unroll
  for (int i = 0; i < 2; ++i)
#pragma unroll
    for (int cc = 0; cc < 8; ++cc) {
      float v = (acc[i][cc] + bia[cc]) * scale;
      unsigned short hi = f2bf(v);
      hi_[i][cc] = hi;
      lo_[i][cc] = f2bf(v - bf2f(hi));
    }
  const int n0tok = tt * 32 + tok2 * 2;
  const int bb = n0tok >> 11, n0 = n0tok & 2047;
  if (s == 2) {
    // transpose via LDS: write 2-token dword pairs, read coalesced rows
#pragma unroll
    for (int cc = 0; cc < 8; ++cc) {
      unsigned h2 = (unsigned)hi_[0][cc] | ((unsigned)hi_[1][cc] << 16);
      unsigned l2 = (unsigned)lo_[0][cc] | ((unsigned)lo_[1][cc] << 16);
      sTh[colg * 8 + cc][tok2] = h2;
      sTl[colg * 8 + cc][tok2] = l2;
    }
    __syncthreads();
    // thread t: col = t>>1 (0..127), token half th = t&1 (16 tokens)
    const int col = t >> 1, th = t & 1;
    const int hvb = (ct & 7) * 2;  // first head of this 128-col tile
    const int bbv = tt >> 6;       // batch (uniform per block)
    const int nbase = (tt & 63) * 32 + th * 16;
    size_t row = (size_t)((bbv * H_ + hvb + (col >> 6)) * D_ + (col & 63));
    size_t dst = row * (size_t)N_ + nbase;
    *(uint4*)(Vhi + dst) = *(const uint4*)&sTh[col][th * 8];
    *(uint4*)(Vhi + dst + 8) = *(const uint4*)&sTh[col][th * 8 + 4];
    *(uint4*)(Vlo + dst) = *(const uint4*)&sTl[col][th * 8];
    *(uint4*)(Vlo + dst + 8) = *(const uint4*)&sTl[col][th * 8 + 4];
  } else {
#pragma unroll
    for (int i = 0; i < 2; ++i) {
      u16x8 h8, l8;
#pragma unroll
      for (int cc = 0; cc < 8; ++cc) {
        h8[cc] = hi_[i][cc];
        l8[cc] = lo_[i][cc];
      }
      size_t dst = ((size_t)(bb * H_ + hh) * N_ + (n0 + i)) * D_ + d0;
      *(u16x8*)&hiA[dst] = h8;
      *(u16x8*)&loA[dst] = l8;
    }
  }
}

// ---------------------------------------------------------------------------
// Kernel 2: flash attention. Round-8:
//  - 2-wave blocks (128 threads), 128-row Q-tiles, grid 1024. Per-wave code
//    identical to round 7 (64 rows/wave, VGPR ~120). LDS = sK 16K + sVt 16K +
//    sP 8K = 40 KB -> 4 blocks/CU (grid 1024 = exactly 4/CU), and barriers
//    couple only 2 waves -> 4 independently-phased blocks feed the MFMA pipe.
//  - row-paired 128B XOR layouts (verified 0 conflicts in R7).
//  - no running max; l via ones-MFMA; async dbuf staging, 1 barrier/iter.
// ---------------------------------------------------------------------------
__global__ __launch_bounds__(128, 2) void attn_kernel(
    const unsigned short* __restrict__ Qhi, const unsigned short* __restrict__ Qlo,
    const unsigned short* __restrict__ Khi, const unsigned short* __restrict__ Klo,
    const unsigned short* __restrict__ VThi, const unsigned short* __restrict__ VTlo,
    unsigned* __restrict__ ctxP) {
  __shared__ unsigned short sK[2][2][32 * 64];   // [buf][hi/lo][key*64+d] 128B rows
  __shared__ unsigned short sVt[2][2][64 * 32];  // [buf][hi/lo] row-paired [d][key]
  __shared__ unsigned short sP[2][64 * 32];      // per-wave, row-paired [row][key]

  const int tid = threadIdx.x;
  const int w = tid >> 6, lane = tid & 63;
  const int lid = lane & 15, quad = lane >> 4;
  const int l7 = lid & 7;
  const int id = blockIdx.x;
  const int bh = id & 63;
  const int qt = id >> 6;  // 0..15
  const int b = bh >> 4, h = bh & 15;
  const size_t base = (size_t)bh * N_ * D_;
  const int row0 = qt * 128 + w * 64;

  // Q fragments: 4 m-tiles x 2 k-chunks, hi+lo
  bf16x8 qh[4][2], ql[4][2];
#pragma unroll
  for (int mt = 0; mt < 4; ++mt) {
    int row = row0 + mt * 16 + lid;
    const unsigned short* qph = Qhi + base + (size_t)row * D_;
    const unsigned short* qpl = Qlo + base + (size_t)row * D_;
#pragma unroll
    for (int kc = 0; kc < 2; ++kc) {
      qh[mt][kc] = *(const bf16x8*)(qph + kc * 32 + quad * 8);
      ql[mt][kc] = *(const bf16x8*)(qpl + kc * 32 + quad * 8);
    }
  }

  f32x4 o[4][4], lacc[4];
#pragma unroll
  for (int mt = 0; mt < 4; ++mt) {
    lacc[mt] = (f32x4){0.f, 0.f, 0.f, 0.f};
#pragma unroll
    for (int dnt = 0; dnt < 4; ++dnt) o[mt][dnt] = (f32x4){0.f, 0.f, 0.f, 0.f};
  }

  bf16x8 ones;
#pragma unroll
  for (int j = 0; j < 8; ++j) ones[j] = (short)0x3F80;

  // staging lane constants
  const int lrow = lane >> 3;         // 0..7
  const int lgr = (lane & 7) ^ lrow;  // XOR'd granule

  auto stage = [&](int kt_, int buf_) {
#pragma unroll
    for (int p = 0; p < 2; ++p) {
      // K rows w*16+p*8 .. +7
      size_t gk = base + (size_t)(kt_ * 32 + w * 16 + p * 8 + lrow) * 64 + lgr * 8;
      ASYNC16(Khi + gk, &sK[buf_][0][(w * 16 + p * 8) * 64]);
      ASYNC16(Klo + gk, &sK[buf_][1][(w * 16 + p * 8) * 64]);
      // V pair-rows w*16+p*8 .. +7 ; decode (pr, slot) -> (d, keys)
      int pr = w * 16 + p * 8 + lrow;
      int vd = pr * 2 + (lgr >> 2);
      int vk0 = (lgr & 3) * 8;
      size_t gv = base + (size_t)vd * N_ + kt_ * 32 + vk0;
      ASYNC16(VThi + gv, &sVt[buf_][0][(w * 16 + p * 8) * 64]);
      ASYNC16(VTlo + gv, &sVt[buf_][1][(w * 16 + p * 8) * 64]);
    }
  };

  stage(0, 0);

  for (int kt = 0; kt < N_ / 32; ++kt) {
    const int buf = kt & 1;
    __syncthreads();  // drains tile kt's async loads; fences buf^1 reuse
    if (kt + 1 < N_ / 32) stage(kt + 1, buf ^ 1);

    // ---- S = Q K^T (3-term hi/lo), all 4 m-tiles share each K fragment ----
    f32x4 sc[4][2];
#pragma unroll
    for (int nt = 0; nt < 2; ++nt) {
      int key = nt * 16 + lid;
#pragma unroll
      for (int kc = 0; kc < 2; ++kc) {
        int off = key * 64 + (((kc * 4 + quad) ^ l7) << 3);
        bf16x8 kh_ = *(const bf16x8*)&sK[buf][0][off];
        bf16x8 kl_ = *(const bf16x8*)&sK[buf][1][off];
#pragma unroll
        for (int mt = 0; mt < 4; ++mt) {
          f32x4 c = (kc == 0) ? (f32x4){0.f, 0.f, 0.f, 0.f} : sc[mt][nt];
          c = MFMA(qh[mt][kc], kh_, c);
          c = MFMA(qh[mt][kc], kl_, c);
          c = MFMA(ql[mt][kc], kh_, c);
          sc[mt][nt] = c;
        }
      }
    }

    // ---- P = exp2(S) -> LDS (row-paired layout); pa frags; l-MFMA ----
    bf16x8 pa[4];
#pragma unroll
    for (int mt = 0; mt < 4; ++mt) {
#pragma unroll
      for (int nt = 0; nt < 2; ++nt)
#pragma unroll
        for (int r = 0; r < 4; ++r) {
          float p = __builtin_amdgcn_exp2f(sc[mt][nt][r]);
          int bits = ((nt * 2 + (lid >> 3)) + (r & 1) * 4) ^ (quad * 2 + (r >> 1));
          sP[w][(mt * 8 + quad * 2 + (r >> 1)) * 64 + bits * 8 + l7] = f2bf(p);
        }
      int pbits = (quad + (lid & 1) * 4) ^ ((lid >> 1) & 7);
      pa[mt] = *(const bf16x8*)&sP[w][(mt * 8 + (lid >> 1)) * 64 + (pbits << 3)];
      lacc[mt] = MFMA(pa[mt], ones, lacc[mt]);
    }

    // ---- O += P V (V fragments read ONCE, shared across 4 m-tiles) ----
#pragma unroll
    for (int dnt = 0; dnt < 4; ++dnt) {
      int voff = (dnt * 8 + (lid >> 1)) * 64 +
                 (((quad + (lid & 1) * 4) ^ ((lid >> 1) & 7)) << 3);
      bf16x8 vh = *(const bf16x8*)&sVt[buf][0][voff];
      bf16x8 vl = *(const bf16x8*)&sVt[buf][1][voff];
#pragma unroll
      for (int mt = 0; mt < 4; ++mt) {
        f32x4 c = o[mt][dnt];
        c = MFMA(pa[mt], vh, c);
        c = MFMA(pa[mt], vl, c);
        o[mt][dnt] = c;
      }
    }
  }

  // epilogue: normalize; write ctx packed (hi<<16|lo) at [b*N+row][h*64+col]
#pragma unroll
  for (int mt = 0; mt < 4; ++mt)
#pragma unroll
    for (int r = 0; r < 4; ++r) {
      float inv = 1.0f / lacc[mt][r];
      int row = row0 + mt * 16 + quad * 4 + r;
      unsigned* dst = ctxP + (size_t)(b * N_ + row) * HID + h * 64;
#pragma unroll
      for (int dnt = 0; dnt < 4; ++dnt) {
        float v = o[mt][dnt][r] * inv;
        unsigned short hi = f2bf(v);
        unsigned short lo = f2bf(v - bf2f(hi));
        dst[dnt * 16 + lid] = ((unsigned)hi << 16) | lo;
      }
    }
}

// ---------------------------------------------------------------------------
// Kernel 3: out projection via MFMA (M=8192, N=64, K=1024, 3-term hi/lo)
// + exact GELU. One wave per block, 16 tokens; everything from global (L2).
// ---------------------------------------------------------------------------
__global__ __launch_bounds__(64) void out_kernel(
    const unsigned* __restrict__ ctxP, const unsigned* __restrict__ W2TP,
    const float* __restrict__ b2, float* __restrict__ out) {
  const int lane = threadIdx.x;
  const int lid = lane & 15, quad = lane >> 4;
  const int tok0 = blockIdx.x * 16;

  f32x4 acc[4];
#pragma unroll
  for (int nt = 0; nt < 4; ++nt) acc[nt] = (f32x4){0.f, 0.f, 0.f, 0.f};

  const unsigned* arow = ctxP + (size_t)(tok0 + lid) * HID + quad * 8;

  for (int kc = 0; kc < 32; ++kc) {
    uint4 a0 = *(const uint4*)(arow + kc * 32);
    uint4 a1 = *(const uint4*)(arow + kc * 32 + 4);
    bf16x8 ah, al;
    ah[0] = (short)(a0.x >> 16); al[0] = (short)(a0.x & 0xffff);
    ah[1] = (short)(a0.y >> 16); al[1] = (short)(a0.y & 0xffff);
    ah[2] = (short)(a0.z >> 16); al[2] = (short)(a0.z & 0xffff);
    ah[3] = (short)(a0.w >> 16); al[3] = (short)(a0.w & 0xffff);
    ah[4] = (short)(a1.x >> 16); al[4] = (short)(a1.x & 0xffff);
    ah[5] = (short)(a1.y >> 16); al[5] = (short)(a1.y & 0xffff);
    ah[6] = (short)(a1.z >> 16); al[6] = (short)(a1.z & 0xffff);
    ah[7] = (short)(a1.w >> 16); al[7] = (short)(a1.w & 0xffff);
#pragma unroll
    for (int nt = 0; nt < 4; ++nt) {
      const unsigned* brow =
          W2TP + (size_t)(nt * 16 + lid) * HID + kc * 32 + quad * 8;
      uint4 b0 = *(const uint4*)brow;
      uint4 b1 = *(const uint4*)(brow + 4);
      bf16x8 bh, bl;
      bh[0] = (short)(b0.x >> 16); bl[0] = (short)(b0.x & 0xffff);
      bh[1] = (short)(b0.y >> 16); bl[1] = (short)(b0.y & 0xffff);
      bh[2] = (short)(b0.z >> 16); bl[2] = (short)(b0.z & 0xffff);
      bh[3] = (short)(b0.w >> 16); bl[3] = (short)(b0.w & 0xffff);
      bh[4] = (short)(b1.x >> 16); bl[4] = (short)(b1.x & 0xffff);
      bh[5] = (short)(b1.y >> 16); bl[5] = (short)(b1.y & 0xffff);
      bh[6] = (short)(b1.z >> 16); bl[6] = (short)(b1.z & 0xffff);
      bh[7] = (short)(b1.w >> 16); bl[7] = (short)(b1.w & 0xffff);
      f32x4 c = acc[nt];
      c = MFMA(ah, bh, c);
      c = MFMA(ah, bl, c);
      c = MFMA(al, bh, c);
      acc[nt] = c;
    }
  }

#pragma unroll
  for (int nt = 0; nt < 4; ++nt)
#pragma unroll
    for (int r = 0; r < 4; ++r) {
      int token = tok0 + quad * 4 + r;
      int col = nt * 16 + lid;
      float v = acc[nt][r] + b2[col];
      float g = 0.5f * v * (1.0f + erff(v * 0.70710678118654752f));
      out[(size_t)token * 64 + col] = g;
    }
}

// ---------------------------------------------------------------------------
extern "C" void kernel_launch(void* const* d_in, const int* in_sizes, int n_in,
                              void* d_out, int out_size, void* d_ws, size_t ws_size,
                              hipStream_t stream) {
  const float* X = (const float*)d_in[0];      // [4,2048,64]
  const float* qkv_w = (const float*)d_in[1];  // [64,3072]
  const float* qkv_b = (const float*)d_in[2];  // [3072]
  const float* out_w = (const float*)d_in[3];  // [1024,64]
  const float* out_b = (const float*)d_in[4];  // [64]
  float* out = (float*)d_out;

  const size_t NE = (size_t)B_ * H_ * N_ * D_;  // 8388608 elems per array
  unsigned short* ws16 = (unsigned short*)d_ws;
  unsigned short* Qhi = ws16 + 0 * NE;
  unsigned short* Qlo = ws16 + 1 * NE;
  unsigned short* Khi = ws16 + 2 * NE;
  unsigned short* Klo = ws16 + 3 * NE;
  unsigned short* VThi = ws16 + 4 * NE;  // transposed [B][H][D][N]
  unsigned short* VTlo = ws16 + 5 * NE;
  unsigned* ctxP = (unsigned*)(ws16 + 6 * NE);   // [8192][1024] packed hi|lo
  unsigned* W2TP = ctxP + (size_t)8192 * 1024;   // [64][1024] packed hi|lo

  w2conv<<<256, 256, 0, stream>>>(out_w, W2TP);
  qkv_kernel<<<dim3(24, 256), 256, 0, stream>>>(X, qkv_w, qkv_b, Qhi, Qlo, Khi,
                                                Klo, VThi, VTlo);
  attn_kernel<<<1024, 128, 0, stream>>>(Qhi, Qlo, Khi, Klo, VThi, VTlo, ctxP);
  out_kernel<<<512, 64, 0, stream>>>(ctxP, W2TP, out_b, out);
}

// Round 9
// 278.396 us; speedup vs baseline: 1.1389x; 1.1389x over previous
//
#include <hip/hip_runtime.h>
#include <math.h>

#define B_ 4
#define N_ 2048
#define C_ 64
#define H_ 16
#define D_ 64
#define HID 1024

// fold attention scale (1/8) and log2(e) into Q so softmax uses exp2 directly
#define QSCALE 0.18033688011112042f  // 0.125 * 1.4426950408889634

typedef short bf16x8 __attribute__((ext_vector_type(8)));
typedef unsigned short u16x8 __attribute__((ext_vector_type(8)));
typedef float f32x4 __attribute__((ext_vector_type(4)));

#define MFMA(a, b, c) __builtin_amdgcn_mfma_f32_16x16x32_bf16((a), (b), (c), 0, 0, 0)

typedef __attribute__((address_space(3))) void lds_t;
typedef const __attribute__((address_space(1))) void gbl_t;
// async global->LDS, 16B/lane; LDS dest = wave-uniform base + lane*16
#define ASYNC16(g, l) __builtin_amdgcn_global_load_lds((gbl_t*)(g), (lds_t*)(l), 16, 0, 0)

static __device__ __forceinline__ unsigned short f2bf(float f) {
  unsigned u = __float_as_uint(f);
  u += 0x7FFFu + ((u >> 16) & 1u);  // round-to-nearest-even
  return (unsigned short)(u >> 16);
}
static __device__ __forceinline__ float bf2f(unsigned short h) {
  return __uint_as_float((unsigned)h << 16);
}

// ---------------------------------------------------------------------------
// Kernel 0: convert out_w [1024][64] f32 -> W2T packed (hi<<16|lo) [64][1024]
// ---------------------------------------------------------------------------
__global__ __launch_bounds__(256) void w2conv(const float* __restrict__ W2,
                                              unsigned* __restrict__ W2TP) {
  int idx = blockIdx.x * 256 + threadIdx.x;  // 65536 total
  int k = idx & 1023, col = idx >> 10;
  float v = W2[(size_t)k * 64 + col];
  unsigned short hi = f2bf(v);
  unsigned short lo = f2bf(v - bf2f(hi));
  W2TP[(size_t)col * 1024 + k] = ((unsigned)hi << 16) | lo;
}

// ---------------------------------------------------------------------------
// Kernel 1: QKV projection (K=64) + split into bf16 arrays.
// Q,K hi/lo [B][H][N][D]; V hi only, TRANSPOSED [B][H][D][N] via LDS.
// ---------------------------------------------------------------------------
__global__ __launch_bounds__(256) void qkv_kernel(
    const float* __restrict__ X, const float* __restrict__ W,
    const float* __restrict__ bias,
    unsigned short* __restrict__ Qhi, unsigned short* __restrict__ Qlo,
    unsigned short* __restrict__ Khi, unsigned short* __restrict__ Klo,
    unsigned short* __restrict__ Vhi) {
  __shared__ float Xl[32][68];
  __shared__ float Wl[64][132];
  __shared__ unsigned sTh[128][17];  // V transpose: [col][tokpair]
  const int t = threadIdx.x;
  const int ct = blockIdx.x;
  const int tt = blockIdx.y;

#pragma unroll
  for (int i = 0; i < 2; ++i) {
    int idx = t + 256 * i;
    int tok = idx >> 4, f4 = (idx & 15) * 4;
    *(f32x4*)&Xl[tok][f4] = *(const f32x4*)&X[(size_t)(tt * 32 + tok) * 64 + f4];
  }
#pragma unroll
  for (int i = 0; i < 8; ++i) {
    int idx = t + 256 * i;
    int c = idx >> 5, f4 = (idx & 31) * 4;
    *(f32x4*)&Wl[c][f4] = *(const f32x4*)&W[(size_t)c * 3072 + ct * 128 + f4];
  }
  __syncthreads();

  const int tok2 = t >> 4;  // 16 groups of 2 tokens
  const int colg = t & 15;  // 16 groups of 8 cols
  float acc[2][8];
#pragma unroll
  for (int i = 0; i < 2; ++i)
#pragma unroll
    for (int c = 0; c < 8; ++c) acc[i][c] = 0.f;

#pragma unroll 4
  for (int c4 = 0; c4 < 64; c4 += 4) {
    f32x4 x0 = *(const f32x4*)&Xl[tok2 * 2][c4];
    f32x4 x1 = *(const f32x4*)&Xl[tok2 * 2 + 1][c4];
#pragma unroll
    for (int j = 0; j < 4; ++j) {
      f32x4 wa = *(const f32x4*)&Wl[c4 + j][colg * 8];
      f32x4 wb = *(const f32x4*)&Wl[c4 + j][colg * 8 + 4];
#pragma unroll
      for (int cc = 0; cc < 4; ++cc) {
        acc[0][cc] += x0[j] * wa[cc];
        acc[0][cc + 4] += x0[j] * wb[cc];
        acc[1][cc] += x1[j] * wa[cc];
        acc[1][cc + 4] += x1[j] * wb[cc];
      }
    }
  }

  const int s = ct >> 3;  // 0=q 1=k 2=v (uniform per block)
  const float scale = (s == 0) ? QSCALE : 1.0f;
  const int col0 = ct * 128 + colg * 8;
  const int hh = (col0 >> 6) & 15, d0 = col0 & 63;
  float bia[8];
#pragma unroll
  for (int cc = 0; cc < 8; ++cc) bia[cc] = bias[col0 + cc];

  float v_[2][8];
#pragma unroll
  for (int i = 0; i < 2; ++i)
#pragma unroll
    for (int cc = 0; cc < 8; ++cc) v_[i][cc] = (acc[i][cc] + bia[cc]) * scale;

  const int n0tok = tt * 32 + tok2 * 2;
  const int bb = n0tok >> 11, n0 = n0tok & 2047;
  if (s == 2) {
    // V: hi only, transpose via LDS, coalesced uint4 row stores
#pragma unroll
    for (int cc = 0; cc < 8; ++cc) {
      unsigned h2 = (unsigned)f2bf(v_[0][cc]) | ((unsigned)f2bf(v_[1][cc]) << 16);
      sTh[colg * 8 + cc][tok2] = h2;
    }
    __syncthreads();  // uniform: s is block-uniform
    const int col = t >> 1, th = t & 1;
    const int hvb = (ct & 7) * 2;
    const int bbv = tt >> 6;
    const int nbase = (tt & 63) * 32 + th * 16;
    size_t row = (size_t)((bbv * H_ + hvb + (col >> 6)) * D_ + (col & 63));
    size_t dst = row * (size_t)N_ + nbase;
    *(uint4*)(Vhi + dst) = *(const uint4*)&sTh[col][th * 8];
    *(uint4*)(Vhi + dst + 8) = *(const uint4*)&sTh[col][th * 8 + 4];
  } else {
    unsigned short* hiA = (s == 0) ? Qhi : Khi;
    unsigned short* loA = (s == 0) ? Qlo : Klo;
#pragma unroll
    for (int i = 0; i < 2; ++i) {
      u16x8 h8, l8;
#pragma unroll
      for (int cc = 0; cc < 8; ++cc) {
        unsigned short hi = f2bf(v_[i][cc]);
        h8[cc] = hi;
        l8[cc] = f2bf(v_[i][cc] - bf2f(hi));
      }
      size_t dst = ((size_t)(bb * H_ + hh) * N_ + (n0 + i)) * D_ + d0;
      *(u16x8*)&hiA[dst] = h8;
      *(u16x8*)&loA[dst] = l8;
    }
  }
}

// ---------------------------------------------------------------------------
// Kernel 2: flash attention. Round-9: single-bf16 V (PV 2->1 term, 84->68
// MFMA/iter, V LDS+staging halves); otherwise the R8 structure: 2-wave
// 128-row blocks, grid 1024, row-paired 128B XOR layouts (0 conflicts),
// no running max, l via ones-MFMA, async dbuf staging, 1 barrier/iter.
// LDS = sK 16K + sVt 8K + sP 8K = 32 KB.
// ---------------------------------------------------------------------------
__global__ __launch_bounds__(128, 2) void attn_kernel(
    const unsigned short* __restrict__ Qhi, const unsigned short* __restrict__ Qlo,
    const unsigned short* __restrict__ Khi, const unsigned short* __restrict__ Klo,
    const unsigned short* __restrict__ VThi, unsigned* __restrict__ ctxP) {
  __shared__ unsigned short sK[2][2][32 * 64];  // [buf][hi/lo][key*64+d]
  __shared__ unsigned short sVt[2][64 * 32];    // [buf] row-paired [d][key]
  __shared__ unsigned short sP[2][64 * 32];     // per-wave row-paired [row][key]

  const int tid = threadIdx.x;
  const int w = tid >> 6, lane = tid & 63;
  const int lid = lane & 15, quad = lane >> 4;
  const int l7 = lid & 7;
  const int id = blockIdx.x;
  const int bh = id & 63;
  const int qt = id >> 6;  // 0..15
  const int b = bh >> 4, h = bh & 15;
  const size_t base = (size_t)bh * N_ * D_;
  const int row0 = qt * 128 + w * 64;

  // Q fragments: 4 m-tiles x 2 k-chunks, hi+lo
  bf16x8 qh[4][2], ql[4][2];
#pragma unroll
  for (int mt = 0; mt < 4; ++mt) {
    int row = row0 + mt * 16 + lid;
    const unsigned short* qph = Qhi + base + (size_t)row * D_;
    const unsigned short* qpl = Qlo + base + (size_t)row * D_;
#pragma unroll
    for (int kc = 0; kc < 2; ++kc) {
      qh[mt][kc] = *(const bf16x8*)(qph + kc * 32 + quad * 8);
      ql[mt][kc] = *(const bf16x8*)(qpl + kc * 32 + quad * 8);
    }
  }

  f32x4 o[4][4], lacc[4];
#pragma unroll
  for (int mt = 0; mt < 4; ++mt) {
    lacc[mt] = (f32x4){0.f, 0.f, 0.f, 0.f};
#pragma unroll
    for (int dnt = 0; dnt < 4; ++dnt) o[mt][dnt] = (f32x4){0.f, 0.f, 0.f, 0.f};
  }

  bf16x8 ones;
#pragma unroll
  for (int j = 0; j < 8; ++j) ones[j] = (short)0x3F80;

  // staging lane constants
  const int lrow = lane >> 3;         // 0..7
  const int lgr = (lane & 7) ^ lrow;  // XOR'd granule

  auto stage = [&](int kt_, int buf_) {
#pragma unroll
    for (int p = 0; p < 2; ++p) {
      // K rows w*16+p*8 .. +7
      size_t gk = base + (size_t)(kt_ * 32 + w * 16 + p * 8 + lrow) * 64 + lgr * 8;
      ASYNC16(Khi + gk, &sK[buf_][0][(w * 16 + p * 8) * 64]);
      ASYNC16(Klo + gk, &sK[buf_][1][(w * 16 + p * 8) * 64]);
      // V pair-rows w*16+p*8 .. +7 ; decode (pr, slot) -> (d, keys)
      int pr = w * 16 + p * 8 + lrow;
      int vd = pr * 2 + (lgr >> 2);
      int vk0 = (lgr & 3) * 8;
      size_t gv = base + (size_t)vd * N_ + kt_ * 32 + vk0;
      ASYNC16(VThi + gv, &sVt[buf_][(w * 16 + p * 8) * 64]);
    }
  };

  stage(0, 0);

  for (int kt = 0; kt < N_ / 32; ++kt) {
    const int buf = kt & 1;
    __syncthreads();  // drains tile kt's async loads; fences buf^1 reuse
    if (kt + 1 < N_ / 32) stage(kt + 1, buf ^ 1);

    // ---- S = Q K^T (3-term hi/lo), all 4 m-tiles share each K fragment ----
    f32x4 sc[4][2];
#pragma unroll
    for (int nt = 0; nt < 2; ++nt) {
      int key = nt * 16 + lid;
#pragma unroll
      for (int kc = 0; kc < 2; ++kc) {
        int off = key * 64 + (((kc * 4 + quad) ^ l7) << 3);
        bf16x8 kh_ = *(const bf16x8*)&sK[buf][0][off];
        bf16x8 kl_ = *(const bf16x8*)&sK[buf][1][off];
#pragma unroll
        for (int mt = 0; mt < 4; ++mt) {
          f32x4 c = (kc == 0) ? (f32x4){0.f, 0.f, 0.f, 0.f} : sc[mt][nt];
          c = MFMA(qh[mt][kc], kh_, c);
          c = MFMA(qh[mt][kc], kl_, c);
          c = MFMA(ql[mt][kc], kh_, c);
          sc[mt][nt] = c;
        }
      }
    }

    // ---- P = exp2(S) -> LDS (row-paired layout); pa frags; l-MFMA ----
    bf16x8 pa[4];
#pragma unroll
    for (int mt = 0; mt < 4; ++mt) {
#pragma unroll
      for (int nt = 0; nt < 2; ++nt)
#pragma unroll
        for (int r = 0; r < 4; ++r) {
          float p = __builtin_amdgcn_exp2f(sc[mt][nt][r]);
          int bits = ((nt * 2 + (lid >> 3)) + (r & 1) * 4) ^ (quad * 2 + (r >> 1));
          sP[w][(mt * 8 + quad * 2 + (r >> 1)) * 64 + bits * 8 + l7] = f2bf(p);
        }
      int pbits = (quad + (lid & 1) * 4) ^ ((lid >> 1) & 7);
      pa[mt] = *(const bf16x8*)&sP[w][(mt * 8 + (lid >> 1)) * 64 + (pbits << 3)];
      lacc[mt] = MFMA(pa[mt], ones, lacc[mt]);
    }

    // ---- O += P V (single-term V; fragments shared across 4 m-tiles) ----
#pragma unroll
    for (int dnt = 0; dnt < 4; ++dnt) {
      int voff = (dnt * 8 + (lid >> 1)) * 64 +
                 (((quad + (lid & 1) * 4) ^ ((lid >> 1) & 7)) << 3);
      bf16x8 vh = *(const bf16x8*)&sVt[buf][voff];
#pragma unroll
      for (int mt = 0; mt < 4; ++mt) o[mt][dnt] = MFMA(pa[mt], vh, o[mt][dnt]);
    }
  }

  // epilogue: normalize; write ctx packed (hi<<16|lo) at [b*N+row][h*64+col]
#pragma unroll
  for (int mt = 0; mt < 4; ++mt)
#pragma unroll
    for (int r = 0; r < 4; ++r) {
      float inv = 1.0f / lacc[mt][r];
      int row = row0 + mt * 16 + quad * 4 + r;
      unsigned* dst = ctxP + (size_t)(b * N_ + row) * HID + h * 64;
#pragma unroll
      for (int dnt = 0; dnt < 4; ++dnt) {
        float v = o[mt][dnt][r] * inv;
        unsigned short hi = f2bf(v);
        unsigned short lo = f2bf(v - bf2f(hi));
        dst[dnt * 16 + lid] = ((unsigned)hi << 16) | lo;
      }
    }
}

// ---------------------------------------------------------------------------
// Kernel 3: out projection via MFMA (M=8192, N=64, K=1024, 3-term hi/lo)
// + exact GELU. Round-9: 2-wave blocks, K split across waves, LDS combine.
// ---------------------------------------------------------------------------
__global__ __launch_bounds__(128) void out_kernel(
    const unsigned* __restrict__ ctxP, const unsigned* __restrict__ W2TP,
    const float* __restrict__ b2, float* __restrict__ out) {
  __shared__ float sO[2][4][16][16];  // [wave][nt][row][lid]
  const int tid = threadIdx.x;
  const int w = tid >> 6, lane = tid & 63;
  const int lid = lane & 15, quad = lane >> 4;
  const int tok0 = blockIdx.x * 16;

  f32x4 acc[4];
#pragma unroll
  for (int nt = 0; nt < 4; ++nt) acc[nt] = (f32x4){0.f, 0.f, 0.f, 0.f};

  const unsigned* arow = ctxP + (size_t)(tok0 + lid) * HID + w * 512 + quad * 8;

  for (int kc = 0; kc < 16; ++kc) {
    uint4 a0 = *(const uint4*)(arow + kc * 32);
    uint4 a1 = *(const uint4*)(arow + kc * 32 + 4);
    bf16x8 ah, al;
    ah[0] = (short)(a0.x >> 16); al[0] = (short)(a0.x & 0xffff);
    ah[1] = (short)(a0.y >> 16); al[1] = (short)(a0.y & 0xffff);
    ah[2] = (short)(a0.z >> 16); al[2] = (short)(a0.z & 0xffff);
    ah[3] = (short)(a0.w >> 16); al[3] = (short)(a0.w & 0xffff);
    ah[4] = (short)(a1.x >> 16); al[4] = (short)(a1.x & 0xffff);
    ah[5] = (short)(a1.y >> 16); al[5] = (short)(a1.y & 0xffff);
    ah[6] = (short)(a1.z >> 16); al[6] = (short)(a1.z & 0xffff);
    ah[7] = (short)(a1.w >> 16); al[7] = (short)(a1.w & 0xffff);
#pragma unroll
    for (int nt = 0; nt < 4; ++nt) {
      const unsigned* brow =
          W2TP + (size_t)(nt * 16 + lid) * HID + w * 512 + kc * 32 + quad * 8;
      uint4 b0 = *(const uint4*)brow;
      uint4 b1 = *(const uint4*)(brow + 4);
      bf16x8 bh, bl;
      bh[0] = (short)(b0.x >> 16); bl[0] = (short)(b0.x & 0xffff);
      bh[1] = (short)(b0.y >> 16); bl[1] = (short)(b0.y & 0xffff);
      bh[2] = (short)(b0.z >> 16); bl[2] = (short)(b0.z & 0xffff);
      bh[3] = (short)(b0.w >> 16); bl[3] = (short)(b0.w & 0xffff);
      bh[4] = (short)(b1.x >> 16); bl[4] = (short)(b1.x & 0xffff);
      bh[5] = (short)(b1.y >> 16); bl[5] = (short)(b1.y & 0xffff);
      bh[6] = (short)(b1.z >> 16); bl[6] = (short)(b1.z & 0xffff);
      bh[7] = (short)(b1.w >> 16); bl[7] = (short)(b1.w & 0xffff);
      f32x4 c = acc[nt];
      c = MFMA(ah, bh, c);
      c = MFMA(ah, bl, c);
      c = MFMA(al, bh, c);
      acc[nt] = c;
    }
  }

#pragma unroll
  for (int nt = 0; nt < 4; ++nt)
#pragma unroll
    for (int r = 0; r < 4; ++r) sO[w][nt][quad * 4 + r][lid] = acc[nt][r];
  __syncthreads();
  if (w == 0) {
#pragma unroll
    for (int nt = 0; nt < 4; ++nt)
#pragma unroll
      for (int r = 0; r < 4; ++r) {
        int token = tok0 + quad * 4 + r;
        int col = nt * 16 + lid;
        float v = sO[0][nt][quad * 4 + r][lid] + sO[1][nt][quad * 4 + r][lid] +
                  b2[col];
        float g = 0.5f * v * (1.0f + erff(v * 0.70710678118654752f));
        out[(size_t)token * 64 + col] = g;
      }
  }
}

// ---------------------------------------------------------------------------
extern "C" void kernel_launch(void* const* d_in, const int* in_sizes, int n_in,
                              void* d_out, int out_size, void* d_ws, size_t ws_size,
                              hipStream_t stream) {
  const float* X = (const float*)d_in[0];      // [4,2048,64]
  const float* qkv_w = (const float*)d_in[1];  // [64,3072]
  const float* qkv_b = (const float*)d_in[2];  // [3072]
  const float* out_w = (const float*)d_in[3];  // [1024,64]
  const float* out_b = (const float*)d_in[4];  // [64]
  float* out = (float*)d_out;

  const size_t NE = (size_t)B_ * H_ * N_ * D_;  // 8388608 elems per array
  unsigned short* ws16 = (unsigned short*)d_ws;
  unsigned short* Qhi = ws16 + 0 * NE;
  unsigned short* Qlo = ws16 + 1 * NE;
  unsigned short* Khi = ws16 + 2 * NE;
  unsigned short* Klo = ws16 + 3 * NE;
  unsigned short* VThi = ws16 + 4 * NE;  // transposed [B][H][D][N], hi only
  unsigned* ctxP = (unsigned*)(ws16 + 6 * NE);   // [8192][1024] packed hi|lo
  unsigned* W2TP = ctxP + (size_t)8192 * 1024;   // [64][1024] packed hi|lo

  w2conv<<<256, 256, 0, stream>>>(out_w, W2TP);
  qkv_kernel<<<dim3(24, 256), 256, 0, stream>>>(X, qkv_w, qkv_b, Qhi, Qlo, Khi,
                                                Klo, VThi);
  attn_kernel<<<1024, 128, 0, stream>>>(Qhi, Qlo, Khi, Klo, VThi, ctxP);
  out_kernel<<<512, 128, 0, stream>>>(ctxP, W2TP, out_b, out);
}